// Round 4
// baseline (142.880 us; speedup 1.0000x reference)
//
#include <hip/hip_runtime.h>
#include <hip/hip_bf16.h>
#include <stdint.h>

#define IN_F   2048
#define OUT_F  2048
#define NTOK   8192
#define KAUG   2176   // 2048 + E*R
#define RANKE  128    // E*R
#define SCALING 2.0f
#define NT32   68     // KAUG / 32

typedef float  f32x4 __attribute__((ext_vector_type(4)));
typedef __bf16 bf16x8 __attribute__((ext_vector_type(8)));

#define GLOAD(g, l) __builtin_amdgcn_global_load_lds(                                   \
    (const __attribute__((address_space(1))) unsigned int*)(g),                          \
    (__attribute__((address_space(3))) unsigned int*)(l), 16, 0, 0)
#define PIN()    asm volatile("" ::: "memory")
#define BAR()    __builtin_amdgcn_s_barrier()
#define WAITL()  asm volatile("s_waitcnt lgkmcnt(0)" ::: "memory")
#define WAITV0() asm volatile("s_waitcnt vmcnt(0)" ::: "memory")
#define WAITV4() asm volatile("s_waitcnt vmcnt(4)" ::: "memory")
#define WAITV5() asm volatile("s_waitcnt vmcnt(5)" ::: "memory")
#define WAITV8() asm volatile("s_waitcnt vmcnt(8)" ::: "memory")
#define SB0()    __builtin_amdgcn_sched_barrier(0)

__device__ __forceinline__ unsigned short f2b(float f) {
  union { float f; unsigned u; } v; v.f = f;
  return (unsigned short)((v.u + 0x7FFFu + ((v.u >> 16) & 1u)) >> 16);
}

__device__ __forceinline__ uint4 pack8(float4 a, float4 b) {
  uint4 p;
  p.x = f2b(a.x) | ((unsigned)f2b(a.y) << 16);
  p.y = f2b(a.z) | ((unsigned)f2b(a.w) << 16);
  p.z = f2b(b.x) | ((unsigned)f2b(b.y) << 16);
  p.w = f2b(b.z) | ((unsigned)f2b(b.w) << 16);
  return p;
}

// ---------------------------------------------------------------------------
// Merged pre-pass. Role by blockIdx:
//   [0,2048):     prep — x->bf16 A' (cols 0:2048) + router softmax/top2 -> wsc
//   [2048,4096):  build B' row (weight + lora_B)
//   [4096,4104):  convert lora_A -> Acat bf16
// ---------------------------------------------------------------------------
__global__ __launch_bounds__(256)
void k_pre(const float* __restrict__ x, const float* __restrict__ rw,
           const float* __restrict__ wt, const float* __restrict__ lb,
           const float* __restrict__ la,
           unsigned short* __restrict__ Ap, float* __restrict__ wsc,
           unsigned short* __restrict__ Bp, unsigned short* __restrict__ Ac) {
  const int bid = blockIdx.x;
  const int t = threadIdx.x;

  if (bid >= 4096) {          // ---- convert lora_A: 8 blocks x 16 rows
    const int r0 = (bid - 4096) * 16;
    #pragma unroll
    for (int j = 0; j < 16; ++j) {
      int ch = j * 256 + t;
      int row = r0 + (ch >> 8), col8 = ch & 255;
      const float4* src = (const float4*)(la + (size_t)row * IN_F + col8 * 8);
      *(uint4*)(Ac + (size_t)row * IN_F + col8 * 8) = pack8(src[0], src[1]);
    }
    return;
  }
  if (bid >= 2048) {          // ---- build B' row o
    const int o = bid - 2048;
    const int c = t * 8;
    const float4* src = (const float4*)(wt + (size_t)o * IN_F + c);
    *(uint4*)(Bp + (size_t)o * KAUG + c) = pack8(src[0], src[1]);
    if (t < RANKE) {
      float v = lb[((size_t)(t >> 4) * OUT_F + o) * 16 + (t & 15)];
      Bp[(size_t)o * KAUG + IN_F + t] = f2b(v);
    }
    return;
  }

  // ---- prep role: 4 tokens per block
  const int w = t >> 6, l = t & 63;
  const int n0 = bid * 4;
  {
    const int n = n0 + w;
    const float4* src = (const float4*)(x + (size_t)n * IN_F);
    uint4* dst = (uint4*)(Ap + (size_t)n * KAUG);
    #pragma unroll
    for (int j = 0; j < 4; ++j) {
      int ch = j * 64 + l;
      dst[ch] = pack8(src[2 * ch], src[2 * ch + 1]);
    }
  }
  const int e = t & 7, p = t >> 3;
  float4 wreg[16];
  {
    const float4* wp = (const float4*)(rw + (size_t)e * IN_F + p * 64);
    #pragma unroll
    for (int j = 0; j < 16; ++j) wreg[j] = wp[j];
  }
  float s[4];
  #pragma unroll
  for (int ti = 0; ti < 4; ++ti) {
    const float4* xp = (const float4*)(x + (size_t)(n0 + ti) * IN_F + p * 64);
    float acc = 0.f;
    #pragma unroll
    for (int j = 0; j < 16; ++j) {
      float4 a = xp[j], b = wreg[j];
      acc += a.x * b.x + a.y * b.y + a.z * b.z + a.w * b.w;
    }
    s[ti] = acc;
  }
  #pragma unroll
  for (int ti = 0; ti < 4; ++ti) {
    s[ti] += __shfl_xor(s[ti], 8);
    s[ti] += __shfl_xor(s[ti], 16);
    s[ti] += __shfl_xor(s[ti], 32);
  }
  __shared__ float red[4][4][8];
  if (l < 8) {
    #pragma unroll
    for (int ti = 0; ti < 4; ++ti) red[ti][w][l] = s[ti];
  }
  __syncthreads();
  if (l < 8) {
    float tot = red[w][0][l] + red[w][1][l] + red[w][2][l] + red[w][3][l];
    float m = tot;
    m = fmaxf(m, __shfl_xor(m, 1));
    m = fmaxf(m, __shfl_xor(m, 2));
    m = fmaxf(m, __shfl_xor(m, 4));
    float ex = expf(tot - m);
    float dn = ex;
    dn += __shfl_xor(dn, 1);
    dn += __shfl_xor(dn, 2);
    dn += __shfl_xor(dn, 4);
    float prob = ex / dn;
    float v1 = prob; int i1 = l;
    #pragma unroll
    for (int msk = 1; msk <= 4; msk <<= 1) {
      float ov = __shfl_xor(v1, msk); int oi = __shfl_xor(i1, msk);
      if (ov > v1 || (ov == v1 && oi < i1)) { v1 = ov; i1 = oi; }
    }
    float v2 = (l == i1) ? -1.f : prob; int i2 = l;
    #pragma unroll
    for (int msk = 1; msk <= 4; msk <<= 1) {
      float ov = __shfl_xor(v2, msk); int oi = __shfl_xor(i2, msk);
      if (ov > v2 || (ov == v2 && oi < i2)) { v2 = ov; i2 = oi; }
    }
    float wsum = v1 + v2;
    float wv = (l == i1) ? (v1 / wsum) : ((l == i2) ? (v2 / wsum) : 0.f);
    wsc[(size_t)(n0 + w) * 8 + l] = wv * SCALING;
  }
}

// ---------------------------------------------------------------------------
// LoRA-A GEMM: V = gate-scaled (x_bf16 . Acat^T). 32x128 tile, 256 blocks,
// 4 waves. Ring-3 LDS, counted vmcnt(5).
// ---------------------------------------------------------------------------
__global__ __launch_bounds__(256)
void k_lora(const unsigned short* __restrict__ Ap, const unsigned short* __restrict__ Ac,
            const float* __restrict__ wsc, unsigned short* __restrict__ Vout) {
  __shared__ alignas(16) unsigned short LA[3 * 2048];   // 3 x [32][64]
  __shared__ alignas(16) unsigned short LB[3 * 8192];   // 3 x [128][64]
  const int t = threadIdx.x, bm = blockIdx.x;
  const int w = t >> 6, l = t & 63;
  const int lr = l & 15, lq = l >> 4, lx = l & 7;
  const unsigned short* Ablk = Ap + (size_t)bm * 32 * KAUG;
  const int rr = t >> 3, cs = t & 7;
  const int sc = cs ^ (rr & 7);

  f32x4 acc[2][2];
  #pragma unroll
  for (int i = 0; i < 2; ++i)
    #pragma unroll
    for (int j = 0; j < 2; ++j) acc[i][j] = f32x4{0.f, 0.f, 0.f, 0.f};

  auto stg = [&](int buf, int kt) {
    GLOAD(Ablk + (size_t)rr * KAUG + kt * 64 + sc * 8, LA + buf * 2048 + w * 512);
    #pragma unroll
    for (int r = 0; r < 4; ++r)
      GLOAD(Ac + (size_t)(r * 32 + rr) * IN_F + kt * 64 + sc * 8,
            LB + buf * 8192 + r * 2048 + w * 512);
  };

  const int as0 = (lq ^ lx) * 8, as1 = ((4 + lq) ^ lx) * 8;

  stg(0, 0); stg(1, 1);
  for (int kt = 0; kt < 32; ++kt) {
    if (kt == 31) { WAITV0(); } else { WAITV5(); }
    PIN(); BAR();
    if (kt + 2 < 32) stg((kt + 2) % 3, kt + 2);
    const int buf = kt % 3;
    bf16x8 aF[2][2], bF[2][2];
    #pragma unroll
    for (int mi = 0; mi < 2; ++mi) {
      aF[mi][0] = *(const bf16x8*)(LA + buf * 2048 + lr * 64 + mi * 1024 + as0);
      aF[mi][1] = *(const bf16x8*)(LA + buf * 2048 + lr * 64 + mi * 1024 + as1);
    }
    #pragma unroll
    for (int ni = 0; ni < 2; ++ni) {
      bF[ni][0] = *(const bf16x8*)(LB + buf * 8192 + w * 2048 + lr * 64 + ni * 1024 + as0);
      bF[ni][1] = *(const bf16x8*)(LB + buf * 8192 + w * 2048 + lr * 64 + ni * 1024 + as1);
    }
    #pragma unroll
    for (int mi = 0; mi < 2; ++mi)
      #pragma unroll
      for (int ni = 0; ni < 2; ++ni)
        #pragma unroll
        for (int ks = 0; ks < 2; ++ks)
          acc[mi][ni] = __builtin_amdgcn_mfma_f32_16x16x32_bf16(aF[mi][ks], bF[ni][ks], acc[mi][ni], 0, 0, 0);
  }

  #pragma unroll
  for (int mi = 0; mi < 2; ++mi)
    #pragma unroll
    for (int ni = 0; ni < 2; ++ni)
      #pragma unroll
      for (int j = 0; j < 4; ++j) {
        int row = bm * 32 + mi * 16 + lq * 4 + j;
        int col = w * 32 + ni * 16 + lr;
        float sg = wsc[row * 8 + (col >> 4)];
        Vout[(size_t)row * KAUG + col] = f2b(acc[mi][ni][j] * sg);
      }
}

// ---------------------------------------------------------------------------
// Main GEMM: out[8192][2048] = A'[8192][2176] . B'[2048][2176]^T  (bf16->f32)
// 256x256 tile, BK=32, ring-4 LDS (128KB), 8 waves (2Mx4N).
// 2 phases/K-tile, each: {ds_reads ∥ 2 gload_lds stage(t+3) ∥ 16 MFMA}.
// One counted vmcnt(8)/K-tile -> tiles t+2,t+3 always in flight.
// Bank swizzle: 16B chunk slot = k ^ ((row>>1)&3) (inverse-applied on global src).
// ---------------------------------------------------------------------------
__global__ __launch_bounds__(512, 2)
void k_main(const unsigned short* __restrict__ A, const unsigned short* __restrict__ B,
            float* __restrict__ out) {
  __shared__ alignas(16) unsigned short LDS[65536];   // A: [0,32768) B: [32768,65536) shorts

  const int tid = threadIdx.x;
  const int id = blockIdx.x;
  const int wg = (id & 7) * 32 + (id >> 3);   // XCD-contiguous
  const int bn = wg >> 5, bm = wg & 31;
  const int w = tid >> 6, l = tid & 63;
  const int wr = w >> 2, wc = w & 3;
  const int lr = l & 15;

  const unsigned short* Ablk = A + (size_t)bm * 256 * KAUG;
  const unsigned short* Bblk = B + (size_t)bn * 256 * KAUG;

  // staging: thread covers row rr, 16B chunk cs; swizzle slot on the GLOBAL side
  const int rr = tid >> 2, cs = tid & 3;
  const size_t gOfs = (size_t)rr * KAUG + (size_t)((cs ^ ((rr >> 1) & 3)) * 8);

  // fragment reads: lane lr row-offset, chunk (l>>4), swizzled slot
  const int slotx = (l >> 4) ^ ((lr >> 1) & 3);
  const int abase = (wr * 128 + lr) * 32 + slotx * 8;           // shorts
  const int bbase = 32768 + (wc * 64 + lr) * 32 + slotx * 8;    // shorts

  f32x4 acc[8][4];
  #pragma unroll
  for (int i = 0; i < 8; ++i)
    #pragma unroll
    for (int j = 0; j < 4; ++j) acc[i][j] = f32x4{0.f, 0.f, 0.f, 0.f};
  bf16x8 aF[8], bF[4];

  auto stg = [&](int op, int bufm, int h, int kt) {
    const unsigned short* g = (op ? Bblk : Ablk) + (size_t)(h * 128) * KAUG + (size_t)kt * 32 + gOfs;
    unsigned short* ld = LDS + op * 32768 + bufm * 8192 + h * 4096 + w * 512;
    GLOAD(g, ld);
  };

  // prologue: stage tiles 0,1,2 fully (12 loads); vmcnt(8) -> tile 0 resident
  stg(0, 0, 0, 0); stg(0, 0, 1, 0); stg(1, 0, 0, 0); stg(1, 0, 1, 0);
  stg(0, 1, 0, 1); stg(0, 1, 1, 1); stg(1, 1, 0, 1); stg(1, 1, 1, 1);
  stg(0, 2, 0, 2); stg(0, 2, 1, 2); stg(1, 2, 0, 2); stg(1, 2, 1, 2);
  WAITV8(); PIN(); BAR();

  for (int t = 0; t < NT32; ++t) {
    const int buf = t & 3, sb = (t + 3) & 3;
    const int ab = buf * 8192 + abase, bb = buf * 8192 + bbase;
    // ---- P1: read aF[0..3], bF[0..3]; stage A-halves of t+3; MFMA mi 0..3
    #pragma unroll
    for (int mi = 0; mi < 4; ++mi) aF[mi] = *(const bf16x8*)(LDS + ab + mi * 512);
    #pragma unroll
    for (int ni = 0; ni < 4; ++ni) bF[ni] = *(const bf16x8*)(LDS + bb + ni * 512);
    if (t + 3 < NT32) { stg(0, sb, 0, t + 3); stg(0, sb, 1, t + 3); }
    PIN(); BAR(); WAITL(); SB0();
    __builtin_amdgcn_s_setprio(1);
    #pragma unroll
    for (int mi = 0; mi < 4; ++mi)
      #pragma unroll
      for (int ni = 0; ni < 4; ++ni)
        acc[mi][ni] = __builtin_amdgcn_mfma_f32_16x16x32_bf16(aF[mi], bF[ni], acc[mi][ni], 0, 0, 0);
    __builtin_amdgcn_s_setprio(0);
    PIN(); BAR();
    // ---- P2: read aF[4..7]; stage B-halves of t+3; MFMA mi 4..7; counted wait
    #pragma unroll
    for (int mi = 4; mi < 8; ++mi) aF[mi] = *(const bf16x8*)(LDS + ab + mi * 512);
    if (t + 3 < NT32) { stg(1, sb, 0, t + 3); stg(1, sb, 1, t + 3); }
    PIN(); BAR(); WAITL(); SB0();
    __builtin_amdgcn_s_setprio(1);
    #pragma unroll
    for (int mi = 4; mi < 8; ++mi)
      #pragma unroll
      for (int ni = 0; ni < 4; ++ni)
        acc[mi][ni] = __builtin_amdgcn_mfma_f32_16x16x32_bf16(aF[mi], bF[ni], acc[mi][ni], 0, 0, 0);
    __builtin_amdgcn_s_setprio(0);
    if (t + 3 < NT32) { WAITV8(); }
    else if (t + 2 < NT32) { WAITV4(); }
    else if (t + 1 < NT32) { WAITV0(); }
    PIN(); BAR();
  }

  const int lq = l >> 4;
  #pragma unroll
  for (int mi = 0; mi < 8; ++mi)
    #pragma unroll
    for (int ni = 0; ni < 4; ++ni)
      #pragma unroll
      for (int j = 0; j < 4; ++j) {
        int row = bm * 256 + wr * 128 + mi * 16 + lq * 4 + j;
        int col = bn * 256 + wc * 64 + ni * 16 + lr;
        out[(size_t)row * OUT_F + col] = acc[mi][ni][j];
      }
}

extern "C" void kernel_launch(void* const* d_in, const int* in_sizes, int n_in,
                              void* d_out, int out_size, void* d_ws, size_t ws_size,
                              hipStream_t stream) {
  const float* x  = (const float*)d_in[0];
  const float* wt = (const float*)d_in[1];
  const float* la = (const float*)d_in[2];
  const float* lb = (const float*)d_in[3];
  const float* rw = (const float*)d_in[4];
  float* out = (float*)d_out;
  char* ws = (char*)d_ws;

  unsigned short* Ap  = (unsigned short*)ws;                 // bf16 [8192][2176]
  unsigned short* Bp  = (unsigned short*)(ws + 35651584);    // bf16 [2048][2176]
  unsigned short* Ac  = (unsigned short*)(ws + 44564480);    // bf16 [128][2048]
  float*          wsc = (float*)(ws + 45088768);             // f32  [8192][8]

  k_pre<<<4104, 256, 0, stream>>>(x, rw, wt, lb, la, Ap, wsc, Bp, Ac);
  k_lora<<<NTOK / 32, 256, 0, stream>>>(Ap, Ac, wsc, Ap + IN_F);
  k_main<<<256, 512, 0, stream>>>(Ap, Bp, out);
}